// Round 4
// baseline (1239.810 us; speedup 1.0000x reference)
//
#include <hip/hip_runtime.h>

// GAT pipeline, MI355X (gfx950) — round 7.
// (a) gemm: k-major LDS [slot][row] (conflict-free writes AND reads; round-6
//     pad-40 doubled conflicts to 19.2M) + global_load_lds dwordx4 for B and
//     for bf16-A (gemm2); f32-A (gemm1) stays reg-staged into the same layout.
// (b) edge phase: bucket_csr (391 blocks, 1.5/CU) + gather_finalize + 51MB
//     sorted round-trip replaced by packed-u32 pairs + per-bucket LDS f32
//     accumulation into exclusive partial slices + combine. Per-edge gather is
//     one aligned 32B spack line {as0,as1,hh0..5}.

#define NNODES 100000
#define NEDGES 6400000
#define DIN    768
#define DH1    512
#define DH2    256
#define NEG_SLOPE 0.2f
#define CHUNK  8192
#define NPART  782    // ceil(NEDGES/CHUNK)
#define NBUK   391    // ceil(NNODES/256)
#define SSUB   8      // sub-blocks per bucket in bucket_acc

typedef __bf16 bf16x8 __attribute__((ext_vector_type(8)));
typedef float  f32x4  __attribute__((ext_vector_type(4)));

__device__ __forceinline__ float bf2f(unsigned short h) {
    return __uint_as_float(((unsigned)h) << 16);
}
__device__ __forceinline__ unsigned short f2bf(float f) {
    unsigned u = __float_as_uint(f);
    unsigned r = u + 0x7FFFu + ((u >> 16) & 1u);   // round-nearest-even
    return (unsigned short)(r >> 16);
}
__device__ __forceinline__ float ldf(const void* p, int i, int isf32) {
    return isf32 ? ((const float*)p)[i] : bf2f(((const unsigned short*)p)[i]);
}
__device__ __forceinline__ uint4 packbf8(const float* p) {
    float4 u = *(const float4*)p;
    float4 v = *(const float4*)(p + 4);
    uint4 r;
    r.x = (unsigned)f2bf(u.x) | ((unsigned)f2bf(u.y) << 16);
    r.y = (unsigned)f2bf(u.z) | ((unsigned)f2bf(u.w) << 16);
    r.z = (unsigned)f2bf(v.x) | ((unsigned)f2bf(v.y) << 16);
    r.w = (unsigned)f2bf(v.z) | ((unsigned)f2bf(v.w) << 16);
    return r;
}
// async global->LDS, 16B per lane; LDS dest = wave-uniform base + lane*16.
__device__ __forceinline__ void gload16(const unsigned short* g, unsigned short* l) {
    __builtin_amdgcn_global_load_lds(
        (const __attribute__((address_space(1))) unsigned int*)g,
        (__attribute__((address_space(3))) unsigned int*)l, 16, 0, 0);
}

// flags: [0]=x_f32 [1]=We1_f32 [2]=We2_f32 [3]=Wlin_f32 [4]=Watt_f32
//        [5]=edge_i64 [15]=0 constant
__global__ void detect_dtypes(const unsigned short* x, const unsigned short* we1,
                              const unsigned short* we2, const unsigned short* wlin,
                              const unsigned short* watt, const int* ei, int* flags) {
    __shared__ int cnt;
    int b = blockIdx.x, t = threadIdx.x;
    if (t == 0) cnt = 0;
    __syncthreads();
    if (b < 5) {
        const unsigned short* p = (b == 0) ? x : (b == 1) ? we1 : (b == 2) ? we2
                                  : (b == 3) ? wlin : watt;
        int K = (b == 4) ? 96 : 512;
        int c = 0;
        for (int i = t; i < K; i += 256) {
            int e = (p[2 * i] >> 7) & 0xFF;
            if (e >= 0x66 && e <= 0x8C) c++;
        }
        atomicAdd(&cnt, c);
        __syncthreads();
        if (t == 0) flags[b] = (cnt * 10 < K * 6) ? 1 : 0;
    } else {
        int c = 0;
        for (int i = t; i < 2048; i += 256)
            if (ei[2 * i + 1] != 0) c++;
        atomicAdd(&cnt, c);
        __syncthreads();
        if (t == 0) { flags[5] = (cnt == 0) ? 1 : 0; flags[15] = 0; }
    }
}

__global__ void transpose_conv(const void* in, unsigned short* out, int K, int N,
                               const int* flags, int fidx) {
    int f32 = flags[fidx];
    int idx = blockIdx.x * 256 + threadIdx.x;
    if (idx >= K * N) return;
    int k = idx / N, n = idx - k * N;
    unsigned short v = f32 ? f2bf(((const float*)in)[idx])
                           : ((const unsigned short*)in)[idx];
    out[(size_t)n * K + k] = v;
}

template <bool RELU>
__global__ __launch_bounds__(256)
void gemm_bt(const void* __restrict__ A,
             const unsigned short* __restrict__ Bt,
             const unsigned short* __restrict__ bias,
             unsigned short* __restrict__ C,
             int M, int K, int N, const int* flags, int aidx, int nt_n) {
    // k-major LDS: 16B chunk (slot 0..3, row 0..127) at ushort (slot*128+row)*8.
    // Writes hit banks (row*4)%32, reads hit (row*4)%32 -> uniform 8/bank = min.
    __shared__ unsigned short sA[4096];
    __shared__ unsigned short sB[4096];
    const int af32 = flags[aidx];
    const int tid = threadIdx.x;

    // Bijective XCD-chunk swizzle; logical order N-fastest so blocks sharing
    // one A-panel co-run on one XCD's L2.
    const int nwg = gridDim.x;
    const int bid = blockIdx.x;
    const int xcd = bid & 7, bidx = bid >> 3;
    const int q = nwg >> 3, r = nwg & 7;
    const int logical = (xcd < r ? xcd * (q + 1) : r * (q + 1) + (xcd - r) * q) + bidx;
    const int m0 = (logical / nt_n) * 128;
    const int n0 = (logical % nt_n) * 128;

    const int wave = tid >> 6, lane = tid & 63;

    // f32-A reg-staging path (gemm1): thread (srow=tid>>2, c4=tid&3) stages
    // chunks (c4, srow) and (c4, 64+srow).
    const int srow = tid >> 2;
    const int c4   = tid & 3;
    int ar0 = m0 + srow;      if (ar0 >= M) ar0 = M - 1;
    int ar1 = m0 + 64 + srow; if (ar1 >= M) ar1 = M - 1;
    const float* gA0f = (const float*)A + (size_t)ar0 * K + c4 * 8;
    const float* gA1f = (const float*)A + (size_t)ar1 * K + c4 * 8;
    unsigned short* swA0 = &sA[(c4 * 128 + srow) * 8];
    unsigned short* swA1 = &sA[(c4 * 128 + 64 + srow) * 8];

    // gload_lds path: inst1 wave w lane l -> chunk w*64+l = (slot=w>>1,
    // row=(w&1)*64+l); inst2 -> +2048B = slot+2. Global addr pre-permuted.
    const int grow = ((wave & 1) << 6) + lane;          // 0..127
    int arow = m0 + grow; if (arow >= M) arow = M - 1;
    const unsigned short* gAl1 = (const unsigned short*)A + (size_t)arow * K + (wave >> 1) * 8;
    const unsigned short* gAl2 = gAl1 + 16;
    const unsigned short* gBl1 = Bt + (size_t)(n0 + grow) * K + (wave >> 1) * 8;
    const unsigned short* gBl2 = gBl1 + 16;
    unsigned short* ldsA1 = &sA[wave * 512];
    unsigned short* ldsA2 = &sA[2048 + wave * 512];
    unsigned short* ldsB1 = &sB[wave * 512];
    unsigned short* ldsB2 = &sB[2048 + wave * 512];

    const int wr = wave >> 1, wc = wave & 1;
    const int lr = lane & 15;
    const int aBase = ((lane >> 4) * 128 + wr * 64 + lr) * 8;
    const int bBase = ((lane >> 4) * 128 + wc * 64 + lr) * 8;
    f32x4 acc[4][4] = {};

    for (int k0 = 0; k0 < K; k0 += 32) {
        uint4 a0, a1;
        if (af32) { a0 = packbf8(gA0f + k0); a1 = packbf8(gA1f + k0); }
        __syncthreads();                      // previous tile fully read
        if (af32) {
            *(uint4*)swA0 = a0;
            *(uint4*)swA1 = a1;
        } else {
            gload16(gAl1 + k0, ldsA1);
            gload16(gAl2 + k0, ldsA2);
        }
        gload16(gBl1 + k0, ldsB1);
        gload16(gBl2 + k0, ldsB2);
        __syncthreads();                      // drains vmcnt/lgkm -> tile ready
        bf16x8 aF[4], bF[4];
#pragma unroll
        for (int i = 0; i < 4; i++) aF[i] = *(const bf16x8*)&sA[aBase + i * 128];
#pragma unroll
        for (int j = 0; j < 4; j++) bF[j] = *(const bf16x8*)&sB[bBase + j * 128];
#pragma unroll
        for (int i = 0; i < 4; i++)
#pragma unroll
            for (int j = 0; j < 4; j++)
                acc[i][j] = __builtin_amdgcn_mfma_f32_16x16x32_bf16(aF[i], bF[j], acc[i][j], 0, 0, 0);
    }

    float bv[4];
#pragma unroll
    for (int j = 0; j < 4; j++) bv[j] = bf2f(bias[n0 + wc * 64 + j * 16 + lr]);
#pragma unroll
    for (int i = 0; i < 4; i++) {
        int rbase = m0 + wr * 64 + i * 16 + (lane >> 4) * 4;
#pragma unroll
        for (int r2 = 0; r2 < 4; r2++) {
            int row = rbase + r2;
            if (row < M) {
                size_t base = (size_t)row * N + n0 + wc * 64 + lr;
#pragma unroll
                for (int j = 0; j < 4; j++) {
                    float v = acc[i][j][r2] + bv[j];
                    if (RELU) v = fmaxf(v, 0.f);
                    C[base + j * 16] = f2bf(v);
                }
            }
        }
    }
}

// Emits adst[] and spack[n] = {asrc0, asrc1, hh0..hh5} (32B aligned).
__global__ __launch_bounds__(256)
void node_att(const unsigned short* __restrict__ h2,
              const void* __restrict__ Wlin,
              const unsigned short* __restrict__ blin,
              const void* __restrict__ Watt,
              const void* __restrict__ attS,
              const void* __restrict__ attD,
              float* __restrict__ spack, float* __restrict__ adst,
              const int* flags) {
    __shared__ float sW[256 * 32];
    __shared__ float sh2[8 * 256];
    __shared__ float sH[8 * 32];
    __shared__ float sHH[8 * 6];
    const int wlf = flags[3], waf = flags[4];
    const int tid = threadIdx.x;
    for (int i = tid; i < 256 * 32; i += 256) sW[i] = ldf(Wlin, i, wlf);
    const int n0 = blockIdx.x * 8;
    {
        int e = tid * 8;
        int r = e >> 8;
        int c = e & 255;
        uint4 v = *(const uint4*)(h2 + (size_t)(n0 + r) * 256 + c);
        float* o = &sh2[r * 256 + c];
        o[0] = __uint_as_float(v.x << 16); o[1] = __uint_as_float(v.x & 0xFFFF0000u);
        o[2] = __uint_as_float(v.y << 16); o[3] = __uint_as_float(v.y & 0xFFFF0000u);
        o[4] = __uint_as_float(v.z << 16); o[5] = __uint_as_float(v.z & 0xFFFF0000u);
        o[6] = __uint_as_float(v.w << 16); o[7] = __uint_as_float(v.w & 0xFFFF0000u);
    }
    __syncthreads();
    const int nl = tid >> 5;
    const int c  = tid & 31;
    float acc = bf2f(blin[c]);
    const float* hrow = &sh2[nl * 256];
#pragma unroll 8
    for (int k = 0; k < 256; k++) acc += hrow[k] * sW[k * 32 + c];
    sH[nl * 32 + c] = acc;
    __syncthreads();
    if (tid < 48) {
        int n = tid / 6, j = tid - (tid / 6) * 6;
        float s = 0.f;
#pragma unroll
        for (int k = 0; k < 32; k++) s += sH[n * 32 + k] * ldf(Watt, k * 6 + j, waf);
        sHH[n * 6 + j] = s;
    }
    __syncthreads();
    if (tid < 16) {
        int n = tid >> 1, hd = tid & 1;
        float s = 0.f, d = 0.f;
#pragma unroll
        for (int cc = 0; cc < 3; cc++) {
            float v = sHH[n * 6 + hd * 3 + cc];
            s += v * ldf(attS, hd * 3 + cc, waf);
            d += v * ldf(attD, hd * 3 + cc, waf);
        }
        adst[(size_t)(n0 + n) * 2 + hd] = d;
        spack[(size_t)(n0 + n) * 8 + hd] = s;
    }
    if (tid < 48) {
        int n = tid / 6, j = tid - (tid / 6) * 6;
        spack[(size_t)(n0 + n) * 8 + 2 + j] = sHH[n * 6 + j];
    }
}

// ---- edge phase: bucket partition (LDS atomics) + LDS accumulation ----

// P1: per-(bucket, chunk) coarse histogram of dst>>8.
__global__ __launch_bounds__(256)
void part_hist(const int* __restrict__ ei, unsigned* __restrict__ histG,
               const int* __restrict__ flags) {
    __shared__ unsigned h[NBUK];
    int k = blockIdx.x, t = threadIdx.x;
    for (int i = t; i < NBUK; i += 256) h[i] = 0;
    __syncthreads();
    int e0 = k * CHUNK;
    int e1 = e0 + CHUNK; if (e1 > NEDGES) e1 = NEDGES;
    int i64 = flags[5];
    for (int e = e0 + t; e < e1; e += 256) {
        int d = i64 ? (int)((const long long*)ei)[NEDGES + e] : ei[NEDGES + e];
        atomicAdd(&h[d >> 8], 1u);
    }
    __syncthreads();
    for (int i = t; i < NBUK; i += 256) histG[(size_t)i * NPART + k] = h[i];
}

// P2: per-bucket exclusive scan over chunks; emits bucket totals.
__global__ __launch_bounds__(256)
void part_scan(const unsigned* __restrict__ histG, unsigned* __restrict__ start,
               unsigned* __restrict__ btot) {
    int b = blockIdx.x, t = threadIdx.x;
    const unsigned* col = histG + (size_t)b * NPART;
    unsigned* out = start + (size_t)b * NPART;
    unsigned v[4]; unsigned sum = 0;
#pragma unroll
    for (int i = 0; i < 4; i++) {
        int k = t * 4 + i;
        unsigned x = (k < NPART) ? col[k] : 0;
        v[i] = x; sum += x;
    }
    __shared__ unsigned s[256];
    s[t] = sum; __syncthreads();
    for (int off = 1; off < 256; off <<= 1) {
        unsigned x = (t >= off) ? s[t - off] : 0;
        __syncthreads();
        s[t] += x;
        __syncthreads();
    }
    unsigned ex = s[t] - sum;
    unsigned run = ex;
#pragma unroll
    for (int i = 0; i < 4; i++) {
        int k = t * 4 + i;
        if (k < NPART) out[k] = run;
        run += v[i];
    }
    if (t == 255) btot[b] = s[255];
}

// P3: exclusive scan of bucket totals -> bases (+ grand total at [NBUK]).
__global__ void bucket_base(const unsigned* __restrict__ btot, unsigned* __restrict__ bbase) {
    __shared__ unsigned s[512];
    int t = threadIdx.x;
    unsigned v = (t < NBUK) ? btot[t] : 0;
    s[t] = v;
    __syncthreads();
    for (int off = 1; off < 512; off <<= 1) {
        unsigned x = (t >= off) ? s[t - off] : 0;
        __syncthreads();
        s[t] += x;
        __syncthreads();
    }
    if (t < NBUK) bbase[t] = s[t] - v;
    if (t == NBUK - 1) bbase[NBUK] = s[t];
}

// P4: partition packed (src<<8|dst&255) by coarse bucket via LDS cursors.
__global__ __launch_bounds__(256)
void part_scatter(const int* __restrict__ ei, const unsigned* __restrict__ start,
                  const unsigned* __restrict__ bbase, unsigned* __restrict__ pairs,
                  const int* __restrict__ flags) {
    __shared__ unsigned cur[NBUK];
    int k = blockIdx.x, t = threadIdx.x;
    for (int i = t; i < NBUK; i += 256)
        cur[i] = bbase[i] + start[(size_t)i * NPART + k];
    __syncthreads();
    int e0 = k * CHUNK;
    int e1 = e0 + CHUNK; if (e1 > NEDGES) e1 = NEDGES;
    int i64 = flags[5];
    for (int e = e0 + t; e < e1; e += 256) {
        int s, d;
        if (i64) {
            const long long* E = (const long long*)ei;
            s = (int)E[e];
            d = (int)E[NEDGES + e];
        } else {
            s = ei[e];
            d = ei[NEDGES + e];
        }
        unsigned pos = atomicAdd(&cur[d >> 8], 1u);
        pairs[pos] = ((unsigned)s << 8) | (unsigned)(d & 255);
    }
}

// P5: per-(bucket, sub) LDS f32 accumulation into an exclusive partial slice.
// No global atomics, no zero-init pass, no sorted round-trip.
__global__ __launch_bounds__(256)
void bucket_acc(const unsigned* __restrict__ pairs, const unsigned* __restrict__ bbase,
                const float* __restrict__ spack, const float* __restrict__ adst,
                float* __restrict__ partial) {
    __shared__ float acc[256 * 8];
    __shared__ float sad[512];
    int b = blockIdx.x, s = blockIdx.y, t = threadIdx.x;
    int d0n = b << 8;
    int nd = NNODES - d0n; if (nd > 256) nd = 256;
    for (int i = t; i < 2048; i += 256) acc[i] = 0.f;
    for (int i = t; i < 2 * nd; i += 256) sad[i] = adst[(size_t)d0n * 2 + i];
    unsigned e0 = bbase[b], e1 = bbase[b + 1];
    unsigned per = (e1 - e0 + SSUB - 1) / SSUB;
    unsigned s0 = e0 + s * per;
    unsigned s1 = s0 + per; if (s1 > e1) s1 = e1;
    __syncthreads();
    for (unsigned e = s0 + t; e < s1; e += 256) {
        unsigned p = pairs[e];
        unsigned src = p >> 8, dl = p & 255u;
        float4 q0 = *(const float4*)(spack + 8 * (size_t)src);
        float4 q1 = *(const float4*)(spack + 8 * (size_t)src + 4);
        float a0 = q0.x + sad[2 * dl];     a0 = a0 > 0.f ? a0 : NEG_SLOPE * a0;
        float a1 = q0.y + sad[2 * dl + 1]; a1 = a1 > 0.f ? a1 : NEG_SLOPE * a1;
        float p0 = __expf(fminf(a0, 60.f));
        float p1 = __expf(fminf(a1, 60.f));
        float* a = &acc[dl * 8];
        atomicAdd(&a[0], p0);
        atomicAdd(&a[1], p1);
        atomicAdd(&a[2], p0 * q0.z);
        atomicAdd(&a[3], p0 * q0.w);
        atomicAdd(&a[4], p0 * q1.x);
        atomicAdd(&a[5], p1 * q1.y);
        atomicAdd(&a[6], p1 * q1.z);
        atomicAdd(&a[7], p1 * q1.w);
    }
    __syncthreads();
    float* dst = partial + ((size_t)s * NNODES + d0n) * 8;
    for (int i = t; i < nd * 8; i += 256) dst[i] = acc[i];
}

// Sum SSUB partials + self-loop, normalize, head-mean, bias, store.
__global__ void combine_out(const float* __restrict__ partial, const float* __restrict__ spack,
                            const float* __restrict__ adst,
                            const unsigned short* __restrict__ bias,
                            void* __restrict__ out, const int* __restrict__ flags) {
    int n = blockIdx.x * 256 + threadIdx.x;
    if (n >= NNODES) return;
    float v[8] = {0.f, 0.f, 0.f, 0.f, 0.f, 0.f, 0.f, 0.f};
    for (int s = 0; s < SSUB; s++) {
        const float* p = partial + ((size_t)s * NNODES + n) * 8;
#pragma unroll
        for (int j = 0; j < 8; j++) v[j] += p[j];
    }
    float4 q0 = *(const float4*)(spack + 8 * (size_t)n);
    float4 q1 = *(const float4*)(spack + 8 * (size_t)n + 4);
    float2 ad = *(const float2*)(adst + 2 * (size_t)n);
    float a0 = q0.x + ad.x; a0 = a0 > 0.f ? a0 : NEG_SLOPE * a0;
    float a1 = q0.y + ad.y; a1 = a1 > 0.f ? a1 : NEG_SLOPE * a1;
    float p0 = __expf(fminf(a0, 60.f));
    float p1 = __expf(fminf(a1, 60.f));
    v[0] += p0; v[1] += p1;
    v[2] += p0 * q0.z; v[3] += p0 * q0.w; v[4] += p0 * q1.x;
    v[5] += p1 * q1.y; v[6] += p1 * q1.z; v[7] += p1 * q1.w;
    float o0 = 0.5f * (v[2] / v[0] + v[5] / v[1]) + bf2f(bias[0]);
    float o1 = 0.5f * (v[3] / v[0] + v[6] / v[1]) + bf2f(bias[1]);
    float o2 = 0.5f * (v[4] / v[0] + v[7] / v[1]) + bf2f(bias[2]);
    if (flags[0]) {
        float* o = (float*)out;
        o[3 * (size_t)n + 0] = o0; o[3 * (size_t)n + 1] = o1; o[3 * (size_t)n + 2] = o2;
    } else {
        unsigned short* o = (unsigned short*)out;
        o[3 * (size_t)n + 0] = f2bf(o0); o[3 * (size_t)n + 1] = f2bf(o1); o[3 * (size_t)n + 2] = f2bf(o2);
    }
}

extern "C" void kernel_launch(void* const* d_in, const int* in_sizes, int n_in,
                              void* d_out, int out_size, void* d_ws, size_t ws_size,
                              hipStream_t stream) {
    const unsigned short* x    = (const unsigned short*)d_in[0];
    const int*            ei   = (const int*)d_in[1];
    const unsigned short* We1  = (const unsigned short*)d_in[2];
    const unsigned short* be1  = (const unsigned short*)d_in[3];
    const unsigned short* We2  = (const unsigned short*)d_in[4];
    const unsigned short* be2  = (const unsigned short*)d_in[5];
    const unsigned short* Wlin = (const unsigned short*)d_in[6];
    const unsigned short* blin = (const unsigned short*)d_in[7];
    const unsigned short* Watt = (const unsigned short*)d_in[8];
    const unsigned short* attS = (const unsigned short*)d_in[9];
    const unsigned short* attD = (const unsigned short*)d_in[10];
    const unsigned short* bias = (const unsigned short*)d_in[11];

    char* ws = (char*)d_ws;
    unsigned short* W1t   = (unsigned short*)(ws + 0);          //     786,432
    unsigned short* W2t   = (unsigned short*)(ws + 786432);     //     262,144
    unsigned short* h2    = (unsigned short*)(ws + 1048576);    //  51,200,000
    float*    spack = (float*)(ws + 52248576);                  //   3,200,000
    float*    adst  = (float*)(ws + 55448576);                  //     800,000
    unsigned* btot  = (unsigned*)(ws + 57048576);               //       1,568
    unsigned* bbase = (unsigned*)(ws + 57052672);               //       1,568
    int*      flags = (int*)(ws + 59448576);                    //          64
    unsigned short* h1 = (unsigned short*)(ws + 59448640);      // 102,400,000 (dead after gemm2)
    // pairs/partial/histG/start alias h1 (stream-serialized).
    unsigned* pairs   = (unsigned*)(ws + 59448640);             //  25,600,000
    float*    partial = (float*)(ws + 85048640);                //  25,600,000
    unsigned* histG   = (unsigned*)(ws + 136248640);            //   1,223,048
    unsigned* start   = (unsigned*)(ws + 137471744);            //   1,223,048 (end ~138.7MB)
    (void)ws_size; (void)in_sizes; (void)n_in; (void)out_size;

    detect_dtypes<<<6, 256, 0, stream>>>(x, We1, We2, Wlin, Watt, ei, flags);

    transpose_conv<<<(DIN * DH1 + 255) / 256, 256, 0, stream>>>(We1, W1t, DIN, DH1, flags, 1);
    transpose_conv<<<(DH1 * DH2 + 255) / 256, 256, 0, stream>>>(We2, W2t, DH1, DH2, flags, 2);

    dim3 blk(256);
    int nwg1 = ((NNODES + 127) / 128) * (DH1 / 128);   // 782*4 = 3128
    gemm_bt<true><<<nwg1, blk, 0, stream>>>(x, W1t, be1, h1, NNODES, DIN, DH1,
                                            flags, 0, DH1 / 128);
    int nwg2 = ((NNODES + 127) / 128) * (DH2 / 128);   // 782*2 = 1564
    gemm_bt<false><<<nwg2, blk, 0, stream>>>(h1, W2t, be2, h2, NNODES, DH1, DH2,
                                             flags, 15, DH2 / 128);

    node_att<<<NNODES / 8, 256, 0, stream>>>(h2, Wlin, blin, Watt, attS, attD,
                                             spack, adst, flags);

    // ---- edge phase ----
    part_hist<<<NPART, 256, 0, stream>>>(ei, histG, flags);
    part_scan<<<NBUK, 256, 0, stream>>>(histG, start, btot);
    bucket_base<<<1, 512, 0, stream>>>(btot, bbase);
    part_scatter<<<NPART, 256, 0, stream>>>(ei, start, bbase, pairs, flags);
    bucket_acc<<<dim3(NBUK, SSUB), 256, 0, stream>>>(pairs, bbase, spack, adst, partial);
    combine_out<<<(NNODES + 255) / 256, 256, 0, stream>>>(partial, spack, adst,
                                                          bias, d_out, flags);
}